// Round 14
// baseline (1028.734 us; speedup 1.0000x reference)
//
#include <hip/hip_runtime.h>
#include <stdint.h>

typedef unsigned short u16;
typedef unsigned int u32;
typedef unsigned long long u64;

#define NB 16
#define NP 4096
#define NCH 64
#define NS 1024
#define NK 32
#define H1D 128
#define H2D 256
#define KP1 96
#define LDA 104
#define LDH 136
#define OUTOFF (NB * NS * H2D) /* 4194304 */

typedef __attribute__((ext_vector_type(8))) short bfrag;
typedef __attribute__((ext_vector_type(4))) float facc4;
typedef __attribute__((ext_vector_type(2))) float f32x2;

__device__ __forceinline__ u16 f2bf(float f) {
  u32 u = __float_as_uint(f);
  u += 0x7FFFu + ((u >> 16) & 1u);
  return (u16)(u >> 16);
}

// Exactly replicates jnp.sum((a-b)**2, axis=-1): ((dx*dx+dy*dy)+dz*dz), no fma.
__device__ __forceinline__ float dist2(float ax, float ay, float az,
                                       float bx, float by, float bz) {
#pragma clang fp contract(off)
  float dx = ax - bx, dy = ay - by, dz = az - bz;
  return dx * dx + dy * dy + dz * dz;
}

// Pairwise dist2: identical per-element IEEE arithmetic, packed f32x2 ops.
__device__ __forceinline__ f32x2 dist2v(f32x2 ax, f32x2 ay, f32x2 az,
                                        float bx, float by, float bz) {
#pragma clang fp contract(off)
  f32x2 dx = ax - bx, dy = ay - by, dz = az - bz;
  return dx * dx + dy * dy + dz * dz;
}

// Full-wave (64-lane) max via DPP on the VALU pipe; result returned uniform.
__device__ __forceinline__ float wave_max_f32(float v) {
  const int NI = (int)0xFF800000u;  // -inf bits = identity for max
  v = fmaxf(v, __int_as_float(__builtin_amdgcn_update_dpp(NI, __float_as_int(v), 0x111, 0xf, 0xf, false)));
  v = fmaxf(v, __int_as_float(__builtin_amdgcn_update_dpp(NI, __float_as_int(v), 0x112, 0xf, 0xf, false)));
  v = fmaxf(v, __int_as_float(__builtin_amdgcn_update_dpp(NI, __float_as_int(v), 0x114, 0xf, 0xf, false)));
  v = fmaxf(v, __int_as_float(__builtin_amdgcn_update_dpp(NI, __float_as_int(v), 0x118, 0xf, 0xf, false)));
  v = fmaxf(v, __int_as_float(__builtin_amdgcn_update_dpp(NI, __float_as_int(v), 0x142, 0xa, 0xf, false)));
  v = fmaxf(v, __int_as_float(__builtin_amdgcn_update_dpp(NI, __float_as_int(v), 0x143, 0xc, 0xf, false)));
  return __int_as_float(__builtin_amdgcn_readlane(__float_as_int(v), 63));
}

// Full-wave (64-lane) min of u32 via DPP; result returned uniform. (ballq)
__device__ __forceinline__ u32 wave_min_u32(u32 v) {
  u32 t;
  t = (u32)__builtin_amdgcn_update_dpp(-1, (int)v, 0x111, 0xf, 0xf, false); v = t < v ? t : v;
  t = (u32)__builtin_amdgcn_update_dpp(-1, (int)v, 0x112, 0xf, 0xf, false); v = t < v ? t : v;
  t = (u32)__builtin_amdgcn_update_dpp(-1, (int)v, 0x114, 0xf, 0xf, false); v = t < v ? t : v;
  t = (u32)__builtin_amdgcn_update_dpp(-1, (int)v, 0x118, 0xf, 0xf, false); v = t < v ? t : v;
  t = (u32)__builtin_amdgcn_update_dpp(-1, (int)v, 0x142, 0xa, 0xf, false); v = t < v ? t : v;
  t = (u32)__builtin_amdgcn_update_dpp(-1, (int)v, 0x143, 0xc, 0xf, false); v = t < v ? t : v;
  return (u32)__builtin_amdgcn_readlane((int)v, 63);
}

// One step of a 4-slot quad_perm butterfly carrying (key, x, y, z).
#define QUAD_MAX_STEP(CTRL)                                                           \
  {                                                                                   \
    const u32 plo = (u32)__builtin_amdgcn_update_dpp(0, (int)klo, (CTRL), 0xf, 0xf, true); \
    const u32 phi = (u32)__builtin_amdgcn_update_dpp(0, (int)khi, (CTRL), 0xf, 0xf, true); \
    const u32 pqx = (u32)__builtin_amdgcn_update_dpp(0, (int)qxu, (CTRL), 0xf, 0xf, true); \
    const u32 pqy = (u32)__builtin_amdgcn_update_dpp(0, (int)qyu, (CTRL), 0xf, 0xf, true); \
    const u32 pqz = (u32)__builtin_amdgcn_update_dpp(0, (int)qzu, (CTRL), 0xf, 0xf, true); \
    const u64 ok = ((u64)phi << 32) | plo;                                            \
    const u64 mk = ((u64)khi << 32) | klo;                                            \
    if (ok > mk) { klo = plo; khi = phi; qxu = pqx; qyu = pqy; qzu = pqz; }           \
  }

// ---------------- K0: transpose + pad + bf16-convert weights ----------------
__global__ void setup_kernel(const float* __restrict__ W1, const float* __restrict__ W2,
                             u16* __restrict__ W1T, u16* __restrict__ W2T) {
  int idx = blockIdx.x * 256 + threadIdx.x;
  if (idx < H1D * KP1) {
    int n = idx / KP1, k = idx % KP1;
    W1T[idx] = f2bf(k < 67 ? W1[k * H1D + n] : 0.f);
  } else if (idx < H1D * KP1 + H2D * H1D) {
    int j = idx - H1D * KP1;
    int n = j / H1D, k = j % H1D;
    W2T[j] = f2bf(W2[k * H2D + n]);
  }
}

// ---------------- K1: farthest point sampling (1 block per cloud) ----------------
// Round-13 structure (672 us) with ONE dependence-shape change: the in-loop
// sequential 16-step argmax accumulation (cmp+cndmask chain through bv, ~130cy)
// is replaced by an fmax TREE (depth 4) + 16 INDEPENDENT equality one-hot bits
// + OR-tree + v_ffbl (first set bit = smallest j = first occurrence, since
// p = tid*16+j is ascending in j). Value and index are bit-identical: fmax of
// finite non-negative values returns the exact max, and equality against it
// marks exactly the tied elements.
__global__ __launch_bounds__(256) void fps_kernel(const float* __restrict__ pos,
                                                  int* __restrict__ samp,
                                                  float* __restrict__ pos_s) {
  __shared__ float4 plds[NP];                  // 64 KiB: pos as float4
  __shared__ __align__(16) u32 recs[2][4][8];  // 2 buf x 4 waves x 20B record
  __shared__ u16 gilist[NS];                   // 2 KiB: winner index per iter
  const int b = blockIdx.x;
  const int tid = threadIdx.x;
  const int lane = tid & 63, wv = tid >> 6;
  const float* pb = pos + (size_t)b * NP * 3;
  for (int k = tid; k < NP; k += 256)
    plds[k] = make_float4(pb[k * 3 + 0], pb[k * 3 + 1], pb[k * 3 + 2], 0.f);
  if (tid == 0) gilist[0] = 0;
  __syncthreads();

  f32x2 px2[8], py2[8], pz2[8], dd[8];
  const float4 q0 = plds[0];
  float bv = -1.f;
  int bj = 0;
#pragma unroll
  for (int t = 0; t < 8; ++t) {
    const float4 pA = plds[tid * 16 + 2 * t];      // one-time conflicty staging,
    const float4 pB = plds[tid * 16 + 2 * t + 1];  // amortized over 1023 iters
    px2[t] = (f32x2){pA.x, pB.x};
    py2[t] = (f32x2){pA.y, pB.y};
    pz2[t] = (f32x2){pA.z, pB.z};
    const f32x2 s = dist2v(px2[t], py2[t], pz2[t], q0.x, q0.y, q0.z);
    dd[t] = s;
    // ascending p = tid*16 + 2t(+1); strict > => first occurrence
    const bool c0 = s.x > bv; bv = c0 ? s.x : bv; bj = c0 ? 2 * t : bj;
    const bool c1 = s.y > bv; bv = c1 ? s.y : bv; bj = c1 ? 2 * t + 1 : bj;
  }

  for (int i = 1; i < NS; ++i) {
    const int gidx = tid * 16 + bj;
    const float4 cpos = plds[gidx];  // speculative; hides under the DPP chain
    const float wmax = wave_max_f32(bv);
    // winner = first (lowest) lane with bv == wmax  ==  min gidx among ties
    const u64 mask = __ballot(bv == wmax);
    const bool winner = (bv == wmax) && ((mask & ((1ull << lane) - 1ull)) == 0ull);
    if (winner) {
      u32* rp = &recs[i & 1][wv][0];
      *(uint4*)rp = make_uint4(4095u - (u32)gidx, __float_as_uint(bv),
                               __float_as_uint(cpos.x), __float_as_uint(cpos.y));
      rp[4] = __float_as_uint(cpos.z);
    }
    __syncthreads();  // drains LDS only — no global ops in the loop
    // all lanes: read record (lane&3), 2-step quad butterfly -> uniform winner
    const u32* sp = &recs[i & 1][lane & 3][0];
    const uint4 rA = *(const uint4*)sp;
    u32 klo = rA.x, khi = rA.y, qxu = rA.z, qyu = rA.w, qzu = sp[4];
    QUAD_MAX_STEP(0xB1)  // quad_perm [1,0,3,2]
    QUAD_MAX_STEP(0x4E)  // quad_perm [2,3,0,1]
    const float qx = __uint_as_float(qxu);
    const float qy = __uint_as_float(qyu);
    const float qz = __uint_as_float(qzu);
    if (tid == 0) gilist[i] = (u16)(4095 - (int)(klo & 0xFFFu));  // LDS only
    // fused d-update (packed), chain-free
#pragma unroll
    for (int t = 0; t < 8; ++t) {
      const f32x2 s = dist2v(px2[t], py2[t], pz2[t], qx, qy, qz);
      dd[t].x = fminf(dd[t].x, s.x);
      dd[t].y = fminf(dd[t].y, s.y);
    }
    // local argmax: fmax tree (depth 4) + one-hot eq-mask + OR-tree + ffbl
    float v8[8];
#pragma unroll
    for (int t = 0; t < 8; ++t) v8[t] = fmaxf(dd[t].x, dd[t].y);
    const float m0 = fmaxf(fmaxf(v8[0], v8[1]), fmaxf(v8[2], v8[3]));
    const float m1 = fmaxf(fmaxf(v8[4], v8[5]), fmaxf(v8[6], v8[7]));
    bv = fmaxf(m0, m1);
    u32 e8[8];
#pragma unroll
    for (int t = 0; t < 8; ++t)
      e8[t] = ((dd[t].x == bv) ? (1u << (2 * t)) : 0u) |
              ((dd[t].y == bv) ? (1u << (2 * t + 1)) : 0u);
    const u32 msk = (e8[0] | e8[1]) | (e8[2] | e8[3]) |
                    ((e8[4] | e8[5]) | (e8[6] | e8[7]));
    bj = (int)__builtin_ctz(msk);  // lowest set bit = smallest j = first occ.
  }
  __syncthreads();
  // deferred global writes: 4 strided passes, one-time cost
  for (int k = tid; k < NS; k += 256) {
    const int gi = (int)gilist[k];
    const float4 q = plds[gi];
    samp[b * NS + k] = gi;
    pos_s[((size_t)b * NS + k) * 3 + 0] = q.x;
    pos_s[((size_t)b * NS + k) * 3 + 1] = q.y;
    pos_s[((size_t)b * NS + k) * 3 + 2] = q.z;
  }
}

// ---------------- K2: merged ball-query + MFMA MLP + maxpool ----------------
// ballq body (verified r7 form) writes s_nbr/s_nc to LDS instead of global nbr;
// one barrier; then the mlp body (verified r7 form) reads them. qbuf (8 KB)
// overlays the A tile (26.6 KB). LDS 62 KB -> 2 blocks/CU. Saves a kernel
// launch + the nbr global round trip; pos rows stay warm in L1/L2 for staging.
__global__ __launch_bounds__(256) void tail_kernel(
    const float* __restrict__ x, const float* __restrict__ pos,
    const float* __restrict__ b1, const float* __restrict__ b2,
    const int* __restrict__ samp, const u16* __restrict__ W1T,
    const u16* __restrict__ W2T, const float* __restrict__ pos_s,
    float* __restrict__ out) {
  __shared__ __align__(16) unsigned char smem[61968];
  u64* qbuf = (u64*)smem;             // [4][256] during ballq (8 KB)
  u16* A = (u16*)smem;                // 128 x LDA bf16 (26,624 B), overlays qbuf
  u16* Hs = (u16*)(smem + 26624);     // 128 x LDH bf16 (34,816 B)
  int* s_nbr = (int*)(smem + 61440);  // [4][32]
  int* s_nc = (int*)(smem + 61952);   // [4]
  const int tid = threadIdx.x;
  const int lane = tid & 63, w = tid >> 6;
  const int ctr0 = blockIdx.x * 4;
  const int b = ctr0 >> 10;
  const float* pb = pos + (size_t)b * NP * 3;
  {  // ---- ballq: wave w -> centroid ctr0+w ----
    const int nc = samp[ctr0 + w];
    const float cx = pb[nc * 3 + 0], cy = pb[nc * 3 + 1], cz = pb[nc * 3 + 2];
    const float r2 = (float)(0.2 * 0.2);  // matches Python RADIUS*RADIUS -> f32
    u64* qb = qbuf + (size_t)w * 256;
    int V = 0;
    for (int c = 0; c < 64; ++c) {
      const int i = c * 64 + lane;
      const float d2v = dist2(cx, cy, cz, pb[i * 3 + 0], pb[i * 3 + 1], pb[i * 3 + 2]);
      const bool valid = d2v <= r2;
      const u64 bal = __ballot(valid);
      if (valid) {
        const int rank = __popcll(bal & ((1ull << lane) - 1ull));
        const int p = V + rank;
        if (p < 256) qb[p] = ((u64)__float_as_uint(d2v) << 32) | (u32)i;
      }
      V += __popcll(bal);
    }
    if (V > 256) V = 256;  // P(V>256) ~ 1e-21 per query (mean 137, sd 11.5)
    u32 kd[4], ki[4];
#pragma unroll
    for (int t = 0; t < 4; ++t) {
      const int p = t * 64 + lane;
      const u64 v = (p < V) ? qb[p] : ~0ull;
      kd[t] = (u32)(v >> 32);
      ki[t] = (u32)v;
    }
    u32 my = 0, pad = 0;
    for (int e = 0; e < 32; ++e) {
      u32 m0 = kd[0] < kd[1] ? kd[0] : kd[1];
      u32 m1 = kd[2] < kd[3] ? kd[2] : kd[3];
      const u32 m = wave_min_u32(m0 < m1 ? m0 : m1);
      u32 ci = 0xFFFFFFFFu;
#pragma unroll
      for (int t = 0; t < 4; ++t) {
        const u32 cm = (ki[t] < ci) ? ki[t] : ci;
        ci = (kd[t] == m) ? cm : ci;
      }
      const u32 wi = wave_min_u32(ci);
      if (e == 0) pad = wi;  // centroid itself (d2 = 0) is always valid
      const u32 sel = (m == 0xFFFFFFFFu) ? pad : wi;
      if (lane == e) my = sel;
#pragma unroll
      for (int t = 0; t < 4; ++t)
        if (ki[t] == wi) kd[t] = 0xFFFFFFFFu;
    }
    if (lane < 32) s_nbr[w * 32 + lane] = (int)my;
    if (lane == 0) s_nc[w] = nc;
  }
  __syncthreads();  // qbuf dead from here; A may overlay it
  {  // ---- stage A tile: 128 rows x 96 cols bf16 (x | rel | zeros) ----
    const int row = tid >> 1, half = tid & 1;
    const int g = ctr0 + (row >> 5);
    const int n = s_nbr[(row >> 5) * 32 + (row & 31)];
    const float4* xr = (const float4*)(x + ((size_t)b * NP + n) * NCH + half * 32);
#pragma unroll
    for (int qq = 0; qq < 4; ++qq) {
      const float4 v0 = xr[2 * qq], v1 = xr[2 * qq + 1];
      uint4 wp;
      wp.x = (u32)f2bf(v0.x) | ((u32)f2bf(v0.y) << 16);
      wp.y = (u32)f2bf(v0.z) | ((u32)f2bf(v0.w) << 16);
      wp.z = (u32)f2bf(v1.x) | ((u32)f2bf(v1.y) << 16);
      wp.w = (u32)f2bf(v1.z) | ((u32)f2bf(v1.w) << 16);
      *(uint4*)&A[row * LDA + half * 32 + qq * 8] = wp;
    }
    if (half == 0) {
      const float rx = pos[((size_t)b * NP + n) * 3 + 0] - pos_s[(size_t)g * 3 + 0];
      const float ry = pos[((size_t)b * NP + n) * 3 + 1] - pos_s[(size_t)g * 3 + 1];
      const float rz = pos[((size_t)b * NP + n) * 3 + 2] - pos_s[(size_t)g * 3 + 2];
      uint4 wr;
      wr.x = (u32)f2bf(rx) | ((u32)f2bf(ry) << 16);
      wr.y = (u32)f2bf(rz);
      wr.z = 0; wr.w = 0;
      uint4 wz;
      wz.x = wz.y = wz.z = wz.w = 0;
      *(uint4*)&A[row * LDA + 64] = wr;
      *(uint4*)&A[row * LDA + 72] = wz;
      *(uint4*)&A[row * LDA + 80] = wz;
      *(uint4*)&A[row * LDA + 88] = wz;
    }
  }
  __syncthreads();
  const int r16 = lane & 15, g4 = lane >> 4;
  {  // layer 1 (swapped operands): lane l holds m=l&15, n=g4*4+r
    bfrag af[2][3];
#pragma unroll
    for (int mg2 = 0; mg2 < 2; ++mg2)
#pragma unroll
      for (int ks = 0; ks < 3; ++ks)
        af[mg2][ks] = *(const bfrag*)&A[((2 * w + mg2) * 16 + r16) * LDA + ks * 32 + g4 * 8];
#pragma unroll
    for (int ng = 0; ng < 8; ++ng) {
      const bfrag bw0 = *(const bfrag*)&W1T[(ng * 16 + r16) * KP1 + 0 + g4 * 8];
      const bfrag bw1 = *(const bfrag*)&W1T[(ng * 16 + r16) * KP1 + 32 + g4 * 8];
      const bfrag bw2 = *(const bfrag*)&W1T[(ng * 16 + r16) * KP1 + 64 + g4 * 8];
      facc4 a0 = {0.f, 0.f, 0.f, 0.f}, a1 = {0.f, 0.f, 0.f, 0.f};
      a0 = __builtin_amdgcn_mfma_f32_16x16x32_bf16(bw0, af[0][0], a0, 0, 0, 0);
      a0 = __builtin_amdgcn_mfma_f32_16x16x32_bf16(bw1, af[0][1], a0, 0, 0, 0);
      a0 = __builtin_amdgcn_mfma_f32_16x16x32_bf16(bw2, af[0][2], a0, 0, 0, 0);
      a1 = __builtin_amdgcn_mfma_f32_16x16x32_bf16(bw0, af[1][0], a1, 0, 0, 0);
      a1 = __builtin_amdgcn_mfma_f32_16x16x32_bf16(bw1, af[1][1], a1, 0, 0, 0);
      a1 = __builtin_amdgcn_mfma_f32_16x16x32_bf16(bw2, af[1][2], a1, 0, 0, 0);
      const float4 bias4 = *(const float4*)&b1[ng * 16 + g4 * 4];
      const int nb = ng * 16 + g4 * 4;
      u32 lo0 = (u32)f2bf(fmaxf(a0[0] + bias4.x, 0.f)) | ((u32)f2bf(fmaxf(a0[1] + bias4.y, 0.f)) << 16);
      u32 hi0 = (u32)f2bf(fmaxf(a0[2] + bias4.z, 0.f)) | ((u32)f2bf(fmaxf(a0[3] + bias4.w, 0.f)) << 16);
      u32 lo1 = (u32)f2bf(fmaxf(a1[0] + bias4.x, 0.f)) | ((u32)f2bf(fmaxf(a1[1] + bias4.y, 0.f)) << 16);
      u32 hi1 = (u32)f2bf(fmaxf(a1[2] + bias4.z, 0.f)) | ((u32)f2bf(fmaxf(a1[3] + bias4.w, 0.f)) << 16);
      *(uint2*)&Hs[((2 * w + 0) * 16 + r16) * LDH + nb] = make_uint2(lo0, hi0);
      *(uint2*)&Hs[((2 * w + 1) * 16 + r16) * LDH + nb] = make_uint2(lo1, hi1);
    }
  }
  __syncthreads();
  {  // layer 2 + maxpool: wave w owns centroid ctr0+w (m rows 32w..32w+31)
    bfrag hf[2][4];
#pragma unroll
    for (int mg2 = 0; mg2 < 2; ++mg2)
#pragma unroll
      for (int ks = 0; ks < 4; ++ks)
        hf[mg2][ks] = *(const bfrag*)&Hs[((2 * w + mg2) * 16 + r16) * LDH + ks * 32 + g4 * 8];
    const int gout = ctr0 + w;
    const int NI = (int)0xFF800000u;  // -inf
#pragma unroll
    for (int ng = 0; ng < 16; ++ng) {
      facc4 a0 = {0.f, 0.f, 0.f, 0.f}, a1 = {0.f, 0.f, 0.f, 0.f};
#pragma unroll
      for (int ks = 0; ks < 4; ++ks) {
        const bfrag bw = *(const bfrag*)&W2T[(ng * 16 + r16) * H1D + ks * 32 + g4 * 8];
        a0 = __builtin_amdgcn_mfma_f32_16x16x32_bf16(bw, hf[0][ks], a0, 0, 0, 0);
        a1 = __builtin_amdgcn_mfma_f32_16x16x32_bf16(bw, hf[1][ks], a1, 0, 0, 0);
      }
      float v0 = fmaxf(a0[0], a1[0]);
      float v1 = fmaxf(a0[1], a1[1]);
      float v2 = fmaxf(a0[2], a1[2]);
      float v3 = fmaxf(a0[3], a1[3]);
      // max over the 16 m-lanes of each group: row_shr 1/2/4/8 -> lane 15 has max
      v0 = fmaxf(v0, __int_as_float(__builtin_amdgcn_update_dpp(NI, __float_as_int(v0), 0x111, 0xf, 0xf, false)));
      v1 = fmaxf(v1, __int_as_float(__builtin_amdgcn_update_dpp(NI, __float_as_int(v1), 0x111, 0xf, 0xf, false)));
      v2 = fmaxf(v2, __int_as_float(__builtin_amdgcn_update_dpp(NI, __float_as_int(v2), 0x111, 0xf, 0xf, false)));
      v3 = fmaxf(v3, __int_as_float(__builtin_amdgcn_update_dpp(NI, __float_as_int(v3), 0x111, 0xf, 0xf, false)));
      v0 = fmaxf(v0, __int_as_float(__builtin_amdgcn_update_dpp(NI, __float_as_int(v0), 0x112, 0xf, 0xf, false)));
      v1 = fmaxf(v1, __int_as_float(__builtin_amdgcn_update_dpp(NI, __float_as_int(v1), 0x112, 0xf, 0xf, false)));
      v2 = fmaxf(v2, __int_as_float(__builtin_amdgcn_update_dpp(NI, __float_as_int(v2), 0x112, 0xf, 0xf, false)));
      v3 = fmaxf(v3, __int_as_float(__builtin_amdgcn_update_dpp(NI, __float_as_int(v3), 0x112, 0xf, 0xf, false)));
      v0 = fmaxf(v0, __int_as_float(__builtin_amdgcn_update_dpp(NI, __float_as_int(v0), 0x114, 0xf, 0xf, false)));
      v1 = fmaxf(v1, __int_as_float(__builtin_amdgcn_update_dpp(NI, __float_as_int(v1), 0x114, 0xf, 0xf, false)));
      v2 = fmaxf(v2, __int_as_float(__builtin_amdgcn_update_dpp(NI, __float_as_int(v2), 0x114, 0xf, 0xf, false)));
      v3 = fmaxf(v3, __int_as_float(__builtin_amdgcn_update_dpp(NI, __float_as_int(v3), 0x114, 0xf, 0xf, false)));
      v0 = fmaxf(v0, __int_as_float(__builtin_amdgcn_update_dpp(NI, __float_as_int(v0), 0x118, 0xf, 0xf, false)));
      v1 = fmaxf(v1, __int_as_float(__builtin_amdgcn_update_dpp(NI, __float_as_int(v1), 0x118, 0xf, 0xf, false)));
      v2 = fmaxf(v2, __int_as_float(__builtin_amdgcn_update_dpp(NI, __float_as_int(v2), 0x118, 0xf, 0xf, false)));
      v3 = fmaxf(v3, __int_as_float(__builtin_amdgcn_update_dpp(NI, __float_as_int(v3), 0x118, 0xf, 0xf, false)));
      if ((lane & 15) == 15) {
        const float4 b24 = *(const float4*)&b2[ng * 16 + g4 * 4];
        float4 o;
        o.x = fmaxf(v0 + b24.x, 0.f);
        o.y = fmaxf(v1 + b24.y, 0.f);
        o.z = fmaxf(v2 + b24.z, 0.f);
        o.w = fmaxf(v3 + b24.w, 0.f);
        *(float4*)&out[(size_t)gout * H2D + ng * 16 + g4 * 4] = o;
      }
    }
  }
}

extern "C" void kernel_launch(void* const* d_in, const int* in_sizes, int n_in,
                              void* d_out, int out_size, void* d_ws, size_t ws_size,
                              hipStream_t stream) {
  const float* x = (const float*)d_in[0];
  const float* pos = (const float*)d_in[1];
  const float* W1 = (const float*)d_in[2];
  const float* b1 = (const float*)d_in[3];
  const float* W2 = (const float*)d_in[4];
  const float* b2 = (const float*)d_in[5];
  float* out = (float*)d_out;
  char* ws = (char*)d_ws;
  u16* W1T = (u16*)(ws + 0);           // 24576 B
  u16* W2T = (u16*)(ws + 24576);       // 65536 B
  int* samp = (int*)(ws + 90112);      // 65536 B
  float* pos_s = out + OUTOFF;

  setup_kernel<<<dim3(176), dim3(256), 0, stream>>>(W1, W2, W1T, W2T);
  fps_kernel<<<dim3(NB), dim3(256), 0, stream>>>(pos, samp, pos_s);
  tail_kernel<<<dim3(NB * NS / 4), dim3(256), 0, stream>>>(x, pos, b1, b2, samp, W1T,
                                                           W2T, pos_s, out);
}

// Round 15
// 910.671 us; speedup vs baseline: 1.1296x; 1.1296x over previous
//
#include <hip/hip_runtime.h>
#include <stdint.h>

typedef unsigned short u16;
typedef unsigned int u32;
typedef unsigned long long u64;

#define NB 16
#define NP 4096
#define NCH 64
#define NS 1024
#define NK 32
#define H1D 128
#define H2D 256
#define KP1 96
#define LDA 104
#define LDH 136
#define OUTOFF (NB * NS * H2D) /* 4194304 */

typedef __attribute__((ext_vector_type(8))) short bfrag;
typedef __attribute__((ext_vector_type(4))) float facc4;
typedef __attribute__((ext_vector_type(2))) float f32x2;

__device__ __forceinline__ u16 f2bf(float f) {
  u32 u = __float_as_uint(f);
  u += 0x7FFFu + ((u >> 16) & 1u);
  return (u16)(u >> 16);
}

// Exactly replicates jnp.sum((a-b)**2, axis=-1): ((dx*dx+dy*dy)+dz*dz), no fma.
__device__ __forceinline__ float dist2(float ax, float ay, float az,
                                       float bx, float by, float bz) {
#pragma clang fp contract(off)
  float dx = ax - bx, dy = ay - by, dz = az - bz;
  return dx * dx + dy * dy + dz * dz;
}

// Pairwise dist2: identical per-element IEEE arithmetic, packed f32x2 ops.
__device__ __forceinline__ f32x2 dist2v(f32x2 ax, f32x2 ay, f32x2 az,
                                        float bx, float by, float bz) {
#pragma clang fp contract(off)
  f32x2 dx = ax - bx, dy = ay - by, dz = az - bz;
  return dx * dx + dy * dy + dz * dz;
}

// Full-wave (64-lane) max via DPP on the VALU pipe; result returned uniform.
__device__ __forceinline__ float wave_max_f32(float v) {
  const int NI = (int)0xFF800000u;  // -inf bits = identity for max
  v = fmaxf(v, __int_as_float(__builtin_amdgcn_update_dpp(NI, __float_as_int(v), 0x111, 0xf, 0xf, false)));
  v = fmaxf(v, __int_as_float(__builtin_amdgcn_update_dpp(NI, __float_as_int(v), 0x112, 0xf, 0xf, false)));
  v = fmaxf(v, __int_as_float(__builtin_amdgcn_update_dpp(NI, __float_as_int(v), 0x114, 0xf, 0xf, false)));
  v = fmaxf(v, __int_as_float(__builtin_amdgcn_update_dpp(NI, __float_as_int(v), 0x118, 0xf, 0xf, false)));
  v = fmaxf(v, __int_as_float(__builtin_amdgcn_update_dpp(NI, __float_as_int(v), 0x142, 0xa, 0xf, false)));
  v = fmaxf(v, __int_as_float(__builtin_amdgcn_update_dpp(NI, __float_as_int(v), 0x143, 0xc, 0xf, false)));
  return __int_as_float(__builtin_amdgcn_readlane(__float_as_int(v), 63));
}

// Full-wave (64-lane) min of u32 via DPP; result returned uniform. (ballq)
__device__ __forceinline__ u32 wave_min_u32(u32 v) {
  u32 t;
  t = (u32)__builtin_amdgcn_update_dpp(-1, (int)v, 0x111, 0xf, 0xf, false); v = t < v ? t : v;
  t = (u32)__builtin_amdgcn_update_dpp(-1, (int)v, 0x112, 0xf, 0xf, false); v = t < v ? t : v;
  t = (u32)__builtin_amdgcn_update_dpp(-1, (int)v, 0x114, 0xf, 0xf, false); v = t < v ? t : v;
  t = (u32)__builtin_amdgcn_update_dpp(-1, (int)v, 0x118, 0xf, 0xf, false); v = t < v ? t : v;
  t = (u32)__builtin_amdgcn_update_dpp(-1, (int)v, 0x142, 0xa, 0xf, false); v = t < v ? t : v;
  t = (u32)__builtin_amdgcn_update_dpp(-1, (int)v, 0x143, 0xc, 0xf, false); v = t < v ? t : v;
  return (u32)__builtin_amdgcn_readlane((int)v, 63);
}

// One step of a 4-slot quad_perm butterfly carrying (key, x, y, z).
#define QUAD_MAX_STEP(CTRL)                                                           \
  {                                                                                   \
    const u32 plo = (u32)__builtin_amdgcn_update_dpp(0, (int)klo, (CTRL), 0xf, 0xf, true); \
    const u32 phi = (u32)__builtin_amdgcn_update_dpp(0, (int)khi, (CTRL), 0xf, 0xf, true); \
    const u32 pqx = (u32)__builtin_amdgcn_update_dpp(0, (int)qxu, (CTRL), 0xf, 0xf, true); \
    const u32 pqy = (u32)__builtin_amdgcn_update_dpp(0, (int)qyu, (CTRL), 0xf, 0xf, true); \
    const u32 pqz = (u32)__builtin_amdgcn_update_dpp(0, (int)qzu, (CTRL), 0xf, 0xf, true); \
    const u64 ok = ((u64)phi << 32) | plo;                                            \
    const u64 mk = ((u64)khi << 32) | klo;                                            \
    if (ok > mk) { klo = plo; khi = phi; qxu = pqx; qyu = pqy; qzu = pqz; }           \
  }

// ---------------- K0: transpose + pad + bf16-convert weights ----------------
__global__ void setup_kernel(const float* __restrict__ W1, const float* __restrict__ W2,
                             u16* __restrict__ W1T, u16* __restrict__ W2T) {
  int idx = blockIdx.x * 256 + threadIdx.x;
  if (idx < H1D * KP1) {
    int n = idx / KP1, k = idx % KP1;
    W1T[idx] = f2bf(k < 67 ? W1[k * H1D + n] : 0.f);
  } else if (idx < H1D * KP1 + H2D * H1D) {
    int j = idx - H1D * KP1;
    int n = j / H1D, k = j % H1D;
    W2T[j] = f2bf(W2[k * H2D + n]);
  }
}

// ---------------- K1: farthest point sampling (1 block per cloud) ----------------
// Round-13 form verbatim (best measured 672 us): consecutive pts p = tid*16+j,
// value-only DPP chain + ballot first-set-lane tie-break, winner record + quad
// butterfly, zero global ops in the loop (gilist in LDS, deferred stores).
__global__ __launch_bounds__(256) void fps_kernel(const float* __restrict__ pos,
                                                  int* __restrict__ samp,
                                                  float* __restrict__ pos_s) {
  __shared__ float4 plds[NP];                  // 64 KiB: pos as float4
  __shared__ __align__(16) u32 recs[2][4][8];  // 2 buf x 4 waves x 20B record
  __shared__ u16 gilist[NS];                   // 2 KiB: winner index per iter
  const int b = blockIdx.x;
  const int tid = threadIdx.x;
  const int lane = tid & 63, wv = tid >> 6;
  const float* pb = pos + (size_t)b * NP * 3;
  for (int k = tid; k < NP; k += 256)
    plds[k] = make_float4(pb[k * 3 + 0], pb[k * 3 + 1], pb[k * 3 + 2], 0.f);
  if (tid == 0) gilist[0] = 0;
  __syncthreads();

  f32x2 px2[8], py2[8], pz2[8], dd[8];
  const float4 q0 = plds[0];
  float bv = -1.f;
  int bj = 0;
#pragma unroll
  for (int t = 0; t < 8; ++t) {
    const float4 pA = plds[tid * 16 + 2 * t];      // one-time conflicty staging,
    const float4 pB = plds[tid * 16 + 2 * t + 1];  // amortized over 1023 iters
    px2[t] = (f32x2){pA.x, pB.x};
    py2[t] = (f32x2){pA.y, pB.y};
    pz2[t] = (f32x2){pA.z, pB.z};
    const f32x2 s = dist2v(px2[t], py2[t], pz2[t], q0.x, q0.y, q0.z);
    dd[t] = s;
    // ascending p = tid*16 + 2t(+1); strict > => first occurrence
    const bool c0 = s.x > bv; bv = c0 ? s.x : bv; bj = c0 ? 2 * t : bj;
    const bool c1 = s.y > bv; bv = c1 ? s.y : bv; bj = c1 ? 2 * t + 1 : bj;
  }

  for (int i = 1; i < NS; ++i) {
    const int gidx = tid * 16 + bj;
    const float4 cpos = plds[gidx];  // speculative; hides under the DPP chain
    const float wmax = wave_max_f32(bv);
    // winner = first (lowest) lane with bv == wmax  ==  min gidx among ties
    const u64 mask = __ballot(bv == wmax);
    const bool winner = (bv == wmax) && ((mask & ((1ull << lane) - 1ull)) == 0ull);
    if (winner) {
      u32* rp = &recs[i & 1][wv][0];
      *(uint4*)rp = make_uint4(4095u - (u32)gidx, __float_as_uint(bv),
                               __float_as_uint(cpos.x), __float_as_uint(cpos.y));
      rp[4] = __float_as_uint(cpos.z);
    }
    __syncthreads();  // drains LDS only — no global ops in the loop
    // all lanes: read record (lane&3), 2-step quad butterfly -> uniform winner
    const u32* sp = &recs[i & 1][lane & 3][0];
    const uint4 rA = *(const uint4*)sp;
    u32 klo = rA.x, khi = rA.y, qxu = rA.z, qyu = rA.w, qzu = sp[4];
    QUAD_MAX_STEP(0xB1)  // quad_perm [1,0,3,2]
    QUAD_MAX_STEP(0x4E)  // quad_perm [2,3,0,1]
    const float qx = __uint_as_float(qxu);
    const float qy = __uint_as_float(qyu);
    const float qz = __uint_as_float(qzu);
    if (tid == 0) gilist[i] = (u16)(4095 - (int)(klo & 0xFFFu));  // LDS only
    // fused d-update (packed) + next local argmax (scalar on halves)
    bv = -1.f; bj = 0;
#pragma unroll
    for (int t = 0; t < 8; ++t) {
      const f32x2 s = dist2v(px2[t], py2[t], pz2[t], qx, qy, qz);
      dd[t].x = fminf(dd[t].x, s.x);
      dd[t].y = fminf(dd[t].y, s.y);
      const bool c0 = dd[t].x > bv; bv = c0 ? dd[t].x : bv; bj = c0 ? 2 * t : bj;
      const bool c1 = dd[t].y > bv; bv = c1 ? dd[t].y : bv; bj = c1 ? 2 * t + 1 : bj;
    }
  }
  __syncthreads();
  // deferred global writes: 4 strided passes, one-time cost
  for (int k = tid; k < NS; k += 256) {
    const int gi = (int)gilist[k];
    const float4 q = plds[gi];
    samp[b * NS + k] = gi;
    pos_s[((size_t)b * NS + k) * 3 + 0] = q.x;
    pos_s[((size_t)b * NS + k) * 3 + 1] = q.y;
    pos_s[((size_t)b * NS + k) * 3 + 2] = q.z;
  }
}

// ---------------- K2: ball query, exact top-K=32 by (d2, idx) key ----------------
// u32 split-key extraction: DPP v_min_u32 chains (VALU). Small LDS (8 KB) ->
// high occupancy; kept as its own kernel (r14's merge cost ~95 us).
__global__ __launch_bounds__(256) void ballq_kernel(const float* __restrict__ pos,
                                                    const int* __restrict__ samp,
                                                    int* __restrict__ nbr) {
  __shared__ u64 buf[4][256];
  const int lane = threadIdx.x & 63, wv = threadIdx.x >> 6;
  const int sg = blockIdx.x * 4 + wv;
  const int b = sg >> 10;
  const int nc = samp[sg];
  const float* pb = pos + (size_t)b * NP * 3;
  const float cx = pb[nc * 3 + 0], cy = pb[nc * 3 + 1], cz = pb[nc * 3 + 2];
  const float r2 = (float)(0.2 * 0.2);  // matches Python RADIUS*RADIUS -> f32
  int V = 0;
  for (int c = 0; c < 64; ++c) {
    const int i = c * 64 + lane;
    const float d2v = dist2(cx, cy, cz, pb[i * 3 + 0], pb[i * 3 + 1], pb[i * 3 + 2]);
    const bool valid = d2v <= r2;
    const u64 bal = __ballot(valid);
    if (valid) {
      const int rank = __popcll(bal & ((1ull << lane) - 1ull));
      const int p = V + rank;
      if (p < 256) buf[wv][p] = ((u64)__float_as_uint(d2v) << 32) | (u32)i;
    }
    V += __popcll(bal);
  }
  if (V > 256) V = 256;  // P(V>256) ~ 1e-21 per query (mean 137, sd 11.5)
  u32 kd[4], ki[4];
#pragma unroll
  for (int t = 0; t < 4; ++t) {
    const int p = t * 64 + lane;
    const u64 v = (p < V) ? buf[wv][p] : ~0ull;
    kd[t] = (u32)(v >> 32);
    ki[t] = (u32)v;
  }
  u32 my = 0, pad = 0;
  for (int e = 0; e < 32; ++e) {
    // global min d2-bits
    u32 m0 = kd[0] < kd[1] ? kd[0] : kd[1];
    u32 m1 = kd[2] < kd[3] ? kd[2] : kd[3];
    const u32 m = wave_min_u32(m0 < m1 ? m0 : m1);
    // exact tie-break: min idx among entries with kd == m
    u32 ci = 0xFFFFFFFFu;
#pragma unroll
    for (int t = 0; t < 4; ++t) {
      const u32 cm = (ki[t] < ci) ? ki[t] : ci;
      ci = (kd[t] == m) ? cm : ci;
    }
    const u32 wi = wave_min_u32(ci);
    if (e == 0) pad = wi;  // centroid itself (d2 = 0) is always valid
    const u32 sel = (m == 0xFFFFFFFFu) ? pad : wi;
    if (lane == e) my = sel;
    // scrub winner by its globally-unique index
#pragma unroll
    for (int t = 0; t < 4; ++t)
      if (ki[t] == wi) kd[t] = 0xFFFFFFFFu;
  }
  if (lane < 32) nbr[(size_t)sg * NK + lane] = (int)my;
}

// ---------------- K3: gather -> bf16 MFMA MLP (swapped operands) -> maxpool ----
// ONE change vs r13: Hs OVERLAYS A. The A tile is dead once the af fragments
// are in registers, so after an extra barrier the layer-1 outputs reuse its
// LDS. 61.4 KB -> 34.8 KB per block => 4 blocks/CU (was 2): 2x the resident
// waves to hide the gather + W-load latency.
__global__ __launch_bounds__(256) void mlp_kernel(
    const float* __restrict__ x, const float* __restrict__ pos,
    const float* __restrict__ b1, const float* __restrict__ b2,
    const int* __restrict__ nbr, const u16* __restrict__ W1T,
    const u16* __restrict__ W2T, const float* __restrict__ pos_s,
    float* __restrict__ out) {
  __shared__ u16 smem[128 * LDH];  // 34,816 B: A (stride LDA) then Hs (stride LDH)
  u16* A = smem;
  u16* Hs = smem;
  const int ctr0 = blockIdx.x * 4;
  const int b = ctr0 >> 10;
  const int tid = threadIdx.x;
  {  // stage A tile: 128 rows x 96 cols bf16 (x | rel | zeros), stride LDA
    const int row = tid >> 1, half = tid & 1;
    const int g = ctr0 + (row >> 5);
    const int n = nbr[(size_t)g * NK + (row & 31)];
    const float4* xr = (const float4*)(x + ((size_t)b * NP + n) * NCH + half * 32);
#pragma unroll
    for (int qq = 0; qq < 4; ++qq) {
      const float4 v0 = xr[2 * qq], v1 = xr[2 * qq + 1];
      uint4 wp;
      wp.x = (u32)f2bf(v0.x) | ((u32)f2bf(v0.y) << 16);
      wp.y = (u32)f2bf(v0.z) | ((u32)f2bf(v0.w) << 16);
      wp.z = (u32)f2bf(v1.x) | ((u32)f2bf(v1.y) << 16);
      wp.w = (u32)f2bf(v1.z) | ((u32)f2bf(v1.w) << 16);
      *(uint4*)&A[row * LDA + half * 32 + qq * 8] = wp;
    }
    if (half == 0) {
      const float rx = pos[((size_t)b * NP + n) * 3 + 0] - pos_s[(size_t)g * 3 + 0];
      const float ry = pos[((size_t)b * NP + n) * 3 + 1] - pos_s[(size_t)g * 3 + 1];
      const float rz = pos[((size_t)b * NP + n) * 3 + 2] - pos_s[(size_t)g * 3 + 2];
      uint4 wr;
      wr.x = (u32)f2bf(rx) | ((u32)f2bf(ry) << 16);
      wr.y = (u32)f2bf(rz);
      wr.z = 0; wr.w = 0;
      uint4 wz;
      wz.x = wz.y = wz.z = wz.w = 0;
      *(uint4*)&A[row * LDA + 64] = wr;
      *(uint4*)&A[row * LDA + 72] = wz;
      *(uint4*)&A[row * LDA + 80] = wz;
      *(uint4*)&A[row * LDA + 88] = wz;
    }
  }
  __syncthreads();
  const int lane = tid & 63, w = tid >> 6;
  const int r16 = lane & 15, g4 = lane >> 4;
  // load ALL A-fragments into registers; A is dead afterwards
  bfrag af[2][3];
#pragma unroll
  for (int mg2 = 0; mg2 < 2; ++mg2)
#pragma unroll
    for (int ks = 0; ks < 3; ++ks)
      af[mg2][ks] = *(const bfrag*)&A[((2 * w + mg2) * 16 + r16) * LDA + ks * 32 + g4 * 8];
  __syncthreads();  // NEW: everyone finished reading A -> Hs may overlay it
  {  // layer 1 (swapped operands): lane l holds m=l&15, n=g4*4+r
#pragma unroll
    for (int ng = 0; ng < 8; ++ng) {
      const bfrag bw0 = *(const bfrag*)&W1T[(ng * 16 + r16) * KP1 + 0 + g4 * 8];
      const bfrag bw1 = *(const bfrag*)&W1T[(ng * 16 + r16) * KP1 + 32 + g4 * 8];
      const bfrag bw2 = *(const bfrag*)&W1T[(ng * 16 + r16) * KP1 + 64 + g4 * 8];
      facc4 a0 = {0.f, 0.f, 0.f, 0.f}, a1 = {0.f, 0.f, 0.f, 0.f};
      a0 = __builtin_amdgcn_mfma_f32_16x16x32_bf16(bw0, af[0][0], a0, 0, 0, 0);
      a0 = __builtin_amdgcn_mfma_f32_16x16x32_bf16(bw1, af[0][1], a0, 0, 0, 0);
      a0 = __builtin_amdgcn_mfma_f32_16x16x32_bf16(bw2, af[0][2], a0, 0, 0, 0);
      a1 = __builtin_amdgcn_mfma_f32_16x16x32_bf16(bw0, af[1][0], a1, 0, 0, 0);
      a1 = __builtin_amdgcn_mfma_f32_16x16x32_bf16(bw1, af[1][1], a1, 0, 0, 0);
      a1 = __builtin_amdgcn_mfma_f32_16x16x32_bf16(bw2, af[1][2], a1, 0, 0, 0);
      const float4 bias4 = *(const float4*)&b1[ng * 16 + g4 * 4];
      const int nb = ng * 16 + g4 * 4;
      u32 lo0 = (u32)f2bf(fmaxf(a0[0] + bias4.x, 0.f)) | ((u32)f2bf(fmaxf(a0[1] + bias4.y, 0.f)) << 16);
      u32 hi0 = (u32)f2bf(fmaxf(a0[2] + bias4.z, 0.f)) | ((u32)f2bf(fmaxf(a0[3] + bias4.w, 0.f)) << 16);
      u32 lo1 = (u32)f2bf(fmaxf(a1[0] + bias4.x, 0.f)) | ((u32)f2bf(fmaxf(a1[1] + bias4.y, 0.f)) << 16);
      u32 hi1 = (u32)f2bf(fmaxf(a1[2] + bias4.z, 0.f)) | ((u32)f2bf(fmaxf(a1[3] + bias4.w, 0.f)) << 16);
      *(uint2*)&Hs[((2 * w + 0) * 16 + r16) * LDH + nb] = make_uint2(lo0, hi0);
      *(uint2*)&Hs[((2 * w + 1) * 16 + r16) * LDH + nb] = make_uint2(lo1, hi1);
    }
  }
  __syncthreads();
  {  // layer 2 + maxpool: wave w owns centroid ctr0+w (m rows 32w..32w+31)
    bfrag hf[2][4];
#pragma unroll
    for (int mg2 = 0; mg2 < 2; ++mg2)
#pragma unroll
      for (int ks = 0; ks < 4; ++ks)
        hf[mg2][ks] = *(const bfrag*)&Hs[((2 * w + mg2) * 16 + r16) * LDH + ks * 32 + g4 * 8];
    const int gout = ctr0 + w;
    const int NI = (int)0xFF800000u;  // -inf
#pragma unroll
    for (int ng = 0; ng < 16; ++ng) {
      facc4 a0 = {0.f, 0.f, 0.f, 0.f}, a1 = {0.f, 0.f, 0.f, 0.f};
#pragma unroll
      for (int ks = 0; ks < 4; ++ks) {
        const bfrag bw = *(const bfrag*)&W2T[(ng * 16 + r16) * H1D + ks * 32 + g4 * 8];
        a0 = __builtin_amdgcn_mfma_f32_16x16x32_bf16(bw, hf[0][ks], a0, 0, 0, 0);
        a1 = __builtin_amdgcn_mfma_f32_16x16x32_bf16(bw, hf[1][ks], a1, 0, 0, 0);
      }
      float v0 = fmaxf(a0[0], a1[0]);
      float v1 = fmaxf(a0[1], a1[1]);
      float v2 = fmaxf(a0[2], a1[2]);
      float v3 = fmaxf(a0[3], a1[3]);
      // max over the 16 m-lanes of each group: row_shr 1/2/4/8 -> lane 15 has max
      v0 = fmaxf(v0, __int_as_float(__builtin_amdgcn_update_dpp(NI, __float_as_int(v0), 0x111, 0xf, 0xf, false)));
      v1 = fmaxf(v1, __int_as_float(__builtin_amdgcn_update_dpp(NI, __float_as_int(v1), 0x111, 0xf, 0xf, false)));
      v2 = fmaxf(v2, __int_as_float(__builtin_amdgcn_update_dpp(NI, __float_as_int(v2), 0x111, 0xf, 0xf, false)));
      v3 = fmaxf(v3, __int_as_float(__builtin_amdgcn_update_dpp(NI, __float_as_int(v3), 0x111, 0xf, 0xf, false)));
      v0 = fmaxf(v0, __int_as_float(__builtin_amdgcn_update_dpp(NI, __float_as_int(v0), 0x112, 0xf, 0xf, false)));
      v1 = fmaxf(v1, __int_as_float(__builtin_amdgcn_update_dpp(NI, __float_as_int(v1), 0x112, 0xf, 0xf, false)));
      v2 = fmaxf(v2, __int_as_float(__builtin_amdgcn_update_dpp(NI, __float_as_int(v2), 0x112, 0xf, 0xf, false)));
      v3 = fmaxf(v3, __int_as_float(__builtin_amdgcn_update_dpp(NI, __float_as_int(v3), 0x112, 0xf, 0xf, false)));
      v0 = fmaxf(v0, __int_as_float(__builtin_amdgcn_update_dpp(NI, __float_as_int(v0), 0x114, 0xf, 0xf, false)));
      v1 = fmaxf(v1, __int_as_float(__builtin_amdgcn_update_dpp(NI, __float_as_int(v1), 0x114, 0xf, 0xf, false)));
      v2 = fmaxf(v2, __int_as_float(__builtin_amdgcn_update_dpp(NI, __float_as_int(v2), 0x114, 0xf, 0xf, false)));
      v3 = fmaxf(v3, __int_as_float(__builtin_amdgcn_update_dpp(NI, __float_as_int(v3), 0x114, 0xf, 0xf, false)));
      v0 = fmaxf(v0, __int_as_float(__builtin_amdgcn_update_dpp(NI, __float_as_int(v0), 0x118, 0xf, 0xf, false)));
      v1 = fmaxf(v1, __int_as_float(__builtin_amdgcn_update_dpp(NI, __float_as_int(v1), 0x118, 0xf, 0xf, false)));
      v2 = fmaxf(v2, __int_as_float(__builtin_amdgcn_update_dpp(NI, __float_as_int(v2), 0x118, 0xf, 0xf, false)));
      v3 = fmaxf(v3, __int_as_float(__builtin_amdgcn_update_dpp(NI, __float_as_int(v3), 0x118, 0xf, 0xf, false)));
      if ((lane & 15) == 15) {
        const float4 b24 = *(const float4*)&b2[ng * 16 + g4 * 4];
        float4 o;
        o.x = fmaxf(v0 + b24.x, 0.f);
        o.y = fmaxf(v1 + b24.y, 0.f);
        o.z = fmaxf(v2 + b24.z, 0.f);
        o.w = fmaxf(v3 + b24.w, 0.f);
        *(float4*)&out[(size_t)gout * H2D + ng * 16 + g4 * 4] = o;
      }
    }
  }
}

extern "C" void kernel_launch(void* const* d_in, const int* in_sizes, int n_in,
                              void* d_out, int out_size, void* d_ws, size_t ws_size,
                              hipStream_t stream) {
  const float* x = (const float*)d_in[0];
  const float* pos = (const float*)d_in[1];
  const float* W1 = (const float*)d_in[2];
  const float* b1 = (const float*)d_in[3];
  const float* W2 = (const float*)d_in[4];
  const float* b2 = (const float*)d_in[5];
  float* out = (float*)d_out;
  char* ws = (char*)d_ws;
  u16* W1T = (u16*)(ws + 0);           // 24576 B
  u16* W2T = (u16*)(ws + 24576);       // 65536 B
  int* samp = (int*)(ws + 90112);      // 65536 B
  int* nbr = (int*)(ws + 155648);      // 2 MiB
  float* pos_s = out + OUTOFF;

  setup_kernel<<<dim3(176), dim3(256), 0, stream>>>(W1, W2, W1T, W2T);
  fps_kernel<<<dim3(NB), dim3(256), 0, stream>>>(pos, samp, pos_s);
  ballq_kernel<<<dim3(NB * NS / 4), dim3(256), 0, stream>>>(pos, samp, nbr);
  mlp_kernel<<<dim3(NB * NS / 4), dim3(256), 0, stream>>>(x, pos, b1, b2, nbr, W1T, W2T,
                                                          pos_s, out);
}

// Round 16
// 767.202 us; speedup vs baseline: 1.3409x; 1.1870x over previous
//
#include <hip/hip_runtime.h>
#include <stdint.h>

typedef unsigned short u16;
typedef unsigned int u32;
typedef unsigned long long u64;

#define NB 16
#define NP 4096
#define NCH 64
#define NS 1024
#define NK 32
#define H1D 128
#define H2D 256
#define KP1 96
#define LDA 104
#define LDH 136
#define OUTOFF (NB * NS * H2D) /* 4194304 */
#define NCONS 240
#define NGRP 2048 /* 16 clouds x 128 groups of 8 centroids */

typedef __attribute__((ext_vector_type(8))) short bfrag;
typedef __attribute__((ext_vector_type(4))) float facc4;
typedef __attribute__((ext_vector_type(2))) float f32x2;

__device__ __forceinline__ u16 f2bf(float f) {
  u32 u = __float_as_uint(f);
  u += 0x7FFFu + ((u >> 16) & 1u);
  return (u16)(u >> 16);
}

// Exactly replicates jnp.sum((a-b)**2, axis=-1): ((dx*dx+dy*dy)+dz*dz), no fma.
__device__ __forceinline__ float dist2(float ax, float ay, float az,
                                       float bx, float by, float bz) {
#pragma clang fp contract(off)
  float dx = ax - bx, dy = ay - by, dz = az - bz;
  return dx * dx + dy * dy + dz * dz;
}

__device__ __forceinline__ f32x2 dist2v(f32x2 ax, f32x2 ay, f32x2 az,
                                        float bx, float by, float bz) {
#pragma clang fp contract(off)
  f32x2 dx = ax - bx, dy = ay - by, dz = az - bz;
  return dx * dx + dy * dy + dz * dz;
}

__device__ __forceinline__ float wave_max_f32(float v) {
  const int NI = (int)0xFF800000u;
  v = fmaxf(v, __int_as_float(__builtin_amdgcn_update_dpp(NI, __float_as_int(v), 0x111, 0xf, 0xf, false)));
  v = fmaxf(v, __int_as_float(__builtin_amdgcn_update_dpp(NI, __float_as_int(v), 0x112, 0xf, 0xf, false)));
  v = fmaxf(v, __int_as_float(__builtin_amdgcn_update_dpp(NI, __float_as_int(v), 0x114, 0xf, 0xf, false)));
  v = fmaxf(v, __int_as_float(__builtin_amdgcn_update_dpp(NI, __float_as_int(v), 0x118, 0xf, 0xf, false)));
  v = fmaxf(v, __int_as_float(__builtin_amdgcn_update_dpp(NI, __float_as_int(v), 0x142, 0xa, 0xf, false)));
  v = fmaxf(v, __int_as_float(__builtin_amdgcn_update_dpp(NI, __float_as_int(v), 0x143, 0xc, 0xf, false)));
  return __int_as_float(__builtin_amdgcn_readlane(__float_as_int(v), 63));
}

__device__ __forceinline__ u32 wave_min_u32(u32 v) {
  u32 t;
  t = (u32)__builtin_amdgcn_update_dpp(-1, (int)v, 0x111, 0xf, 0xf, false); v = t < v ? t : v;
  t = (u32)__builtin_amdgcn_update_dpp(-1, (int)v, 0x112, 0xf, 0xf, false); v = t < v ? t : v;
  t = (u32)__builtin_amdgcn_update_dpp(-1, (int)v, 0x114, 0xf, 0xf, false); v = t < v ? t : v;
  t = (u32)__builtin_amdgcn_update_dpp(-1, (int)v, 0x118, 0xf, 0xf, false); v = t < v ? t : v;
  t = (u32)__builtin_amdgcn_update_dpp(-1, (int)v, 0x142, 0xa, 0xf, false); v = t < v ? t : v;
  t = (u32)__builtin_amdgcn_update_dpp(-1, (int)v, 0x143, 0xc, 0xf, false); v = t < v ? t : v;
  return (u32)__builtin_amdgcn_readlane((int)v, 63);
}

// 4-slot quad_perm butterfly carrying (key, x, y, z).
#define QUAD_MAX_STEP(CTRL)                                                           \
  {                                                                                   \
    const u32 plo = (u32)__builtin_amdgcn_update_dpp(0, (int)klo, (CTRL), 0xf, 0xf, true); \
    const u32 phi = (u32)__builtin_amdgcn_update_dpp(0, (int)khi, (CTRL), 0xf, 0xf, true); \
    const u32 pqx = (u32)__builtin_amdgcn_update_dpp(0, (int)qxu, (CTRL), 0xf, 0xf, true); \
    const u32 pqy = (u32)__builtin_amdgcn_update_dpp(0, (int)qyu, (CTRL), 0xf, 0xf, true); \
    const u32 pqz = (u32)__builtin_amdgcn_update_dpp(0, (int)qzu, (CTRL), 0xf, 0xf, true); \
    const u64 ok = ((u64)phi << 32) | plo;                                            \
    const u64 mk = ((u64)khi << 32) | klo;                                            \
    if (ok > mk) { klo = plo; khi = phi; qxu = pqx; qyu = pqy; qzu = pqz; }           \
  }

// ---------------- K0: transpose + pad + bf16-convert weights ----------------
__global__ void setup_kernel(const float* __restrict__ W1, const float* __restrict__ W2,
                             u16* __restrict__ W1T, u16* __restrict__ W2T) {
  int idx = blockIdx.x * 256 + threadIdx.x;
  if (idx < H1D * KP1) {
    int n = idx / KP1, k = idx % KP1;
    W1T[idx] = f2bf(k < 67 ? W1[k * H1D + n] : 0.f);
  } else if (idx < H1D * KP1 + H2D * H1D) {
    int j = idx - H1D * KP1;
    int n = j / H1D, k = j % H1D;
    W2T[j] = f2bf(W2[k * H2D + n]);
  }
}

// ---------------- Fused producer/consumer kernel ----------------
// 256 blocks x 512 threads, 123.9 KB LDS -> 1 block/CU -> all co-resident.
// Blocks 0-15: r15 FPS (waves 0-3 compute, ZERO global ops in-loop; winner
// indices -> LDS gilist). Wave 4 lane 0 publishes BATCHES of 16 samp entries
// (sc1 relaxed) + prog RELEASE every 16 iterations — amortizing the sc1 ack
// that made r11's per-iteration publication slow (r13 proved the plain-store
// drain is free; r11's +350us was sc1-per-iter). Waves 5-7 idle at barriers.
// Blocks 16-255: r11's verified consumer (ACQUIRE prog spin -> sc1 samp loads
// -> ballq 8 centroids -> 256-row MFMA MLP). Producers never wait on
// consumers -> no deadlock; prog re-zeroed by captured memset each call.
__global__ __launch_bounds__(512) void fused_kernel(
    const float* __restrict__ x, const float* __restrict__ pos,
    const float* __restrict__ b1, const float* __restrict__ b2,
    const u16* __restrict__ W1T, const u16* __restrict__ W2T,
    int* __restrict__ samp, u32* __restrict__ prog, float* __restrict__ out) {
  __shared__ __align__(16) unsigned char smem[123936];
  const int tid = threadIdx.x;
  const int lane = tid & 63, w = tid >> 6;

  if (blockIdx.x < 16) {
    // ================= producer: FPS for cloud b =================
    float4* plds = (float4*)smem;            // 64 KiB
    u32* recs = (u32*)(smem + 65536);        // [2][4][8] u32
    u16* gilist = (u16*)(smem + 65792);      // 2 KiB
    float* pos_s = out + OUTOFF;
    const int b = blockIdx.x;
    const float* pb = pos + (size_t)b * NP * 3;
    for (int k = tid; k < NP; k += 512)
      plds[k] = make_float4(pb[k * 3 + 0], pb[k * 3 + 1], pb[k * 3 + 2], 0.f);
    if (tid == 0) gilist[0] = 0;
    __syncthreads();

    f32x2 px2[8], py2[8], pz2[8], dd[8];
    float bv = -1.f;
    int bj = 0;
    if (tid < 256) {
      const float4 q0 = plds[0];
#pragma unroll
      for (int t = 0; t < 8; ++t) {
        const float4 pA = plds[tid * 16 + 2 * t];
        const float4 pB = plds[tid * 16 + 2 * t + 1];
        px2[t] = (f32x2){pA.x, pB.x};
        py2[t] = (f32x2){pA.y, pB.y};
        pz2[t] = (f32x2){pA.z, pB.z};
        const f32x2 s = dist2v(px2[t], py2[t], pz2[t], q0.x, q0.y, q0.z);
        dd[t] = s;
        // ascending p = tid*16 + 2t(+1); strict > => first occurrence
        const bool c0 = s.x > bv; bv = c0 ? s.x : bv; bj = c0 ? 2 * t : bj;
        const bool c1 = s.y > bv; bv = c1 ? s.y : bv; bj = c1 ? 2 * t + 1 : bj;
      }
    }

    for (int i = 1; i < NS; ++i) {
      if (tid < 256) {
        const int gidx = tid * 16 + bj;
        const float4 cpos = plds[gidx];  // speculative; hides under DPP chain
        const float wmax = wave_max_f32(bv);
        const u64 mask = __ballot(bv == wmax);
        const bool winner = (bv == wmax) && ((mask & ((1ull << lane) - 1ull)) == 0ull);
        if (winner) {
          u32* rp = &recs[(((i & 1) << 2) + w) * 8];
          *(uint4*)rp = make_uint4(4095u - (u32)gidx, __float_as_uint(bv),
                                   __float_as_uint(cpos.x), __float_as_uint(cpos.y));
          rp[4] = __float_as_uint(cpos.z);
        }
      }
      __syncthreads();  // LDS-only drain for waves 0-3 (no global ops in loop)
      if (tid < 256) {
        const u32* sp = &recs[(((i & 1) << 2) + (lane & 3)) * 8];
        const uint4 rA = *(const uint4*)sp;
        u32 klo = rA.x, khi = rA.y, qxu = rA.z, qyu = rA.w, qzu = sp[4];
        QUAD_MAX_STEP(0xB1)
        QUAD_MAX_STEP(0x4E)
        const float qx = __uint_as_float(qxu);
        const float qy = __uint_as_float(qyu);
        const float qz = __uint_as_float(qzu);
        if (tid == 0) gilist[i] = (u16)(4095 - (int)(klo & 0xFFFu));  // LDS only
        bv = -1.f; bj = 0;
#pragma unroll
        for (int t = 0; t < 8; ++t) {
          const f32x2 s = dist2v(px2[t], py2[t], pz2[t], qx, qy, qz);
          dd[t].x = fminf(dd[t].x, s.x);
          dd[t].y = fminf(dd[t].y, s.y);
          const bool c0 = dd[t].x > bv; bv = c0 ? dd[t].x : bv; bj = c0 ? 2 * t : bj;
          const bool c1 = dd[t].y > bv; bv = c1 ? dd[t].y : bv; bj = c1 ? 2 * t + 1 : bj;
        }
      } else if (w == 4 && lane == 0 && i >= 16 && (i & 15) == 0) {
        // publish batch [i-16, i): gilist entries were all written before the
        // barrier of this iteration (latest is gilist[i-1] from iter i-1).
        // Same-thread relaxed sc1 data stores then RELEASE flag = the r11
        // message-passing pattern, batched. ~600-900cy ack hides in the
        // 1575cy iteration (wave 4 is otherwise idle).
#pragma unroll
        for (int k = 0; k < 16; ++k)
          __hip_atomic_store(&samp[b * NS + (i - 16) + k], (int)gilist[(i - 16) + k],
                             __ATOMIC_RELAXED, __HIP_MEMORY_SCOPE_AGENT);
        __hip_atomic_store(&prog[b], (u32)i, __ATOMIC_RELEASE,
                           __HIP_MEMORY_SCOPE_AGENT);
      }
    }
    __syncthreads();
    if (w == 4 && lane == 0) {
      for (int k = 1008; k < NS; ++k)
        __hip_atomic_store(&samp[b * NS + k], (int)gilist[k], __ATOMIC_RELAXED,
                           __HIP_MEMORY_SCOPE_AGENT);
      __hip_atomic_store(&prog[b], (u32)NS, __ATOMIC_RELEASE,
                         __HIP_MEMORY_SCOPE_AGENT);
    }
    // deferred pos_s writeback (host-read only; plain stores fine)
    for (int k = tid; k < NS; k += 512) {
      const int gi = (int)gilist[k];
      const float4 q = plds[gi];
      pos_s[((size_t)b * NS + k) * 3 + 0] = q.x;
      pos_s[((size_t)b * NS + k) * 3 + 1] = q.y;
      pos_s[((size_t)b * NS + k) * 3 + 2] = q.z;
    }
  } else {
    // ================= consumer: ballq + MLP for groups of 8 =================
    u64* qbuf = (u64*)smem;                    // [8][256] during ballq
    u16* A = (u16*)smem;                       // 256 x LDA bf16 (overlays qbuf)
    u16* Hs = (u16*)(smem + 53248);            // 256 x LDH bf16
    int* s_nbr = (int*)(smem + 122880);        // [8][32]
    int* s_nc = (int*)(smem + 123904);         // [8]
    const int r16 = lane & 15, g4 = lane >> 4;
    for (int G = (int)blockIdx.x - 16; G < NGRP; G += NCONS) {
      const int b = G & 15;
      const int i0 = (G >> 4) << 3;
      if (tid == 0) {
        const u32 need = (u32)(i0 + 8);
        while (__hip_atomic_load(&prog[b], __ATOMIC_ACQUIRE,
                                 __HIP_MEMORY_SCOPE_AGENT) < need)
          __builtin_amdgcn_s_sleep(32);
      }
      __syncthreads();
      // agent-scope loads: bypass this XCD's (possibly stale) caches
      if (tid < 8)
        s_nc[tid] = __hip_atomic_load(&samp[b * NS + i0 + tid], __ATOMIC_RELAXED,
                                      __HIP_MEMORY_SCOPE_AGENT);
      __syncthreads();
      const float* pb = pos + (size_t)b * NP * 3;
      {  // ---- ballq: wave w -> centroid i0+w ----
        const int nc = s_nc[w];
        const float cx = pb[nc * 3 + 0], cy = pb[nc * 3 + 1], cz = pb[nc * 3 + 2];
        const float r2 = (float)(0.2 * 0.2);
        u64* qb = qbuf + (size_t)w * 256;
        int V = 0;
        for (int c = 0; c < 64; ++c) {
          const int i = c * 64 + lane;
          const float d2v = dist2(cx, cy, cz, pb[i * 3 + 0], pb[i * 3 + 1], pb[i * 3 + 2]);
          const bool valid = d2v <= r2;
          const u64 bal = __ballot(valid);
          if (valid) {
            const int rank = __popcll(bal & ((1ull << lane) - 1ull));
            const int p = V + rank;
            if (p < 256) qb[p] = ((u64)__float_as_uint(d2v) << 32) | (u32)i;
          }
          V += __popcll(bal);
        }
        if (V > 256) V = 256;  // P ~ 1e-21 (mean 137, sd 11.5)
        u32 kd[4], ki[4];
#pragma unroll
        for (int t = 0; t < 4; ++t) {
          const int p = t * 64 + lane;
          const u64 v = (p < V) ? qb[p] : ~0ull;
          kd[t] = (u32)(v >> 32);
          ki[t] = (u32)v;
        }
        u32 my = 0, pad = 0;
        for (int e = 0; e < 32; ++e) {
          u32 m0 = kd[0] < kd[1] ? kd[0] : kd[1];
          u32 m1 = kd[2] < kd[3] ? kd[2] : kd[3];
          const u32 m = wave_min_u32(m0 < m1 ? m0 : m1);
          u32 ci = 0xFFFFFFFFu;
#pragma unroll
          for (int t = 0; t < 4; ++t) {
            const u32 cm = (ki[t] < ci) ? ki[t] : ci;
            ci = (kd[t] == m) ? cm : ci;
          }
          const u32 wi = wave_min_u32(ci);
          if (e == 0) pad = wi;
          const u32 sel = (m == 0xFFFFFFFFu) ? pad : wi;
          if (lane == e) my = sel;
#pragma unroll
          for (int t = 0; t < 4; ++t)
            if (ki[t] == wi) kd[t] = 0xFFFFFFFFu;
        }
        if (lane < 32) s_nbr[w * 32 + lane] = (int)my;
      }
      __syncthreads();  // qbuf dead; A may overlay it
      {  // ---- stage A tile: 256 rows x 96 cols bf16 (x | rel | zeros) ----
        const int row = tid >> 1, half = tid & 1;
        const int n = s_nbr[(row >> 5) * 32 + (row & 31)];
        const float4* xr = (const float4*)(x + ((size_t)b * NP + n) * NCH + half * 32);
#pragma unroll
        for (int qq = 0; qq < 4; ++qq) {
          const float4 v0 = xr[2 * qq], v1 = xr[2 * qq + 1];
          uint4 wp;
          wp.x = (u32)f2bf(v0.x) | ((u32)f2bf(v0.y) << 16);
          wp.y = (u32)f2bf(v0.z) | ((u32)f2bf(v0.w) << 16);
          wp.z = (u32)f2bf(v1.x) | ((u32)f2bf(v1.y) << 16);
          wp.w = (u32)f2bf(v1.z) | ((u32)f2bf(v1.w) << 16);
          *(uint4*)&A[row * LDA + half * 32 + qq * 8] = wp;
        }
        if (half == 0) {
          const int ncg = s_nc[row >> 5];
          // bit-identical to pos_j - pos_s (pos_s is a bit-copy of pos rows)
          const float rx = pb[n * 3 + 0] - pb[ncg * 3 + 0];
          const float ry = pb[n * 3 + 1] - pb[ncg * 3 + 1];
          const float rz = pb[n * 3 + 2] - pb[ncg * 3 + 2];
          uint4 wr;
          wr.x = (u32)f2bf(rx) | ((u32)f2bf(ry) << 16);
          wr.y = (u32)f2bf(rz);
          wr.z = 0; wr.w = 0;
          uint4 wz; wz.x = wz.y = wz.z = wz.w = 0;
          *(uint4*)&A[row * LDA + 64] = wr;
          *(uint4*)&A[row * LDA + 72] = wz;
          *(uint4*)&A[row * LDA + 80] = wz;
          *(uint4*)&A[row * LDA + 88] = wz;
        }
      }
      __syncthreads();
      {  // ---- layer 1 (swapped operands): lane l holds m=l&15, n=g4*4+r ----
        bfrag af[2][3];
#pragma unroll
        for (int mg2 = 0; mg2 < 2; ++mg2)
#pragma unroll
          for (int ks = 0; ks < 3; ++ks)
            af[mg2][ks] = *(const bfrag*)&A[((2 * w + mg2) * 16 + r16) * LDA + ks * 32 + g4 * 8];
#pragma unroll
        for (int ng = 0; ng < 8; ++ng) {
          const bfrag bw0 = *(const bfrag*)&W1T[(ng * 16 + r16) * KP1 + 0 + g4 * 8];
          const bfrag bw1 = *(const bfrag*)&W1T[(ng * 16 + r16) * KP1 + 32 + g4 * 8];
          const bfrag bw2 = *(const bfrag*)&W1T[(ng * 16 + r16) * KP1 + 64 + g4 * 8];
          facc4 a0 = {0.f, 0.f, 0.f, 0.f}, a1 = {0.f, 0.f, 0.f, 0.f};
          a0 = __builtin_amdgcn_mfma_f32_16x16x32_bf16(bw0, af[0][0], a0, 0, 0, 0);
          a0 = __builtin_amdgcn_mfma_f32_16x16x32_bf16(bw1, af[0][1], a0, 0, 0, 0);
          a0 = __builtin_amdgcn_mfma_f32_16x16x32_bf16(bw2, af[0][2], a0, 0, 0, 0);
          a1 = __builtin_amdgcn_mfma_f32_16x16x32_bf16(bw0, af[1][0], a1, 0, 0, 0);
          a1 = __builtin_amdgcn_mfma_f32_16x16x32_bf16(bw1, af[1][1], a1, 0, 0, 0);
          a1 = __builtin_amdgcn_mfma_f32_16x16x32_bf16(bw2, af[1][2], a1, 0, 0, 0);
          const float4 bias4 = *(const float4*)&b1[ng * 16 + g4 * 4];
          const int nb = ng * 16 + g4 * 4;
          u32 lo0 = (u32)f2bf(fmaxf(a0[0] + bias4.x, 0.f)) | ((u32)f2bf(fmaxf(a0[1] + bias4.y, 0.f)) << 16);
          u32 hi0 = (u32)f2bf(fmaxf(a0[2] + bias4.z, 0.f)) | ((u32)f2bf(fmaxf(a0[3] + bias4.w, 0.f)) << 16);
          u32 lo1 = (u32)f2bf(fmaxf(a1[0] + bias4.x, 0.f)) | ((u32)f2bf(fmaxf(a1[1] + bias4.y, 0.f)) << 16);
          u32 hi1 = (u32)f2bf(fmaxf(a1[2] + bias4.z, 0.f)) | ((u32)f2bf(fmaxf(a1[3] + bias4.w, 0.f)) << 16);
          *(uint2*)&Hs[((2 * w + 0) * 16 + r16) * LDH + nb] = make_uint2(lo0, hi0);
          *(uint2*)&Hs[((2 * w + 1) * 16 + r16) * LDH + nb] = make_uint2(lo1, hi1);
        }
      }
      __syncthreads();
      {  // ---- layer 2 + maxpool: wave w owns centroid i0+w ----
        bfrag hf[2][4];
#pragma unroll
        for (int mg2 = 0; mg2 < 2; ++mg2)
#pragma unroll
          for (int ks = 0; ks < 4; ++ks)
            hf[mg2][ks] = *(const bfrag*)&Hs[((2 * w + mg2) * 16 + r16) * LDH + ks * 32 + g4 * 8];
        const size_t gout = (size_t)(b * NS + i0 + w);
        const int NI = (int)0xFF800000u;
#pragma unroll
        for (int ng = 0; ng < 16; ++ng) {
          facc4 a0 = {0.f, 0.f, 0.f, 0.f}, a1 = {0.f, 0.f, 0.f, 0.f};
#pragma unroll
          for (int ks = 0; ks < 4; ++ks) {
            const bfrag bw = *(const bfrag*)&W2T[(ng * 16 + r16) * H1D + ks * 32 + g4 * 8];
            a0 = __builtin_amdgcn_mfma_f32_16x16x32_bf16(bw, hf[0][ks], a0, 0, 0, 0);
            a1 = __builtin_amdgcn_mfma_f32_16x16x32_bf16(bw, hf[1][ks], a1, 0, 0, 0);
          }
          float v0 = fmaxf(a0[0], a1[0]);
          float v1 = fmaxf(a0[1], a1[1]);
          float v2 = fmaxf(a0[2], a1[2]);
          float v3 = fmaxf(a0[3], a1[3]);
          v0 = fmaxf(v0, __int_as_float(__builtin_amdgcn_update_dpp(NI, __float_as_int(v0), 0x111, 0xf, 0xf, false)));
          v1 = fmaxf(v1, __int_as_float(__builtin_amdgcn_update_dpp(NI, __float_as_int(v1), 0x111, 0xf, 0xf, false)));
          v2 = fmaxf(v2, __int_as_float(__builtin_amdgcn_update_dpp(NI, __float_as_int(v2), 0x111, 0xf, 0xf, false)));
          v3 = fmaxf(v3, __int_as_float(__builtin_amdgcn_update_dpp(NI, __float_as_int(v3), 0x111, 0xf, 0xf, false)));
          v0 = fmaxf(v0, __int_as_float(__builtin_amdgcn_update_dpp(NI, __float_as_int(v0), 0x112, 0xf, 0xf, false)));
          v1 = fmaxf(v1, __int_as_float(__builtin_amdgcn_update_dpp(NI, __float_as_int(v1), 0x112, 0xf, 0xf, false)));
          v2 = fmaxf(v2, __int_as_float(__builtin_amdgcn_update_dpp(NI, __float_as_int(v2), 0x112, 0xf, 0xf, false)));
          v3 = fmaxf(v3, __int_as_float(__builtin_amdgcn_update_dpp(NI, __float_as_int(v3), 0x112, 0xf, 0xf, false)));
          v0 = fmaxf(v0, __int_as_float(__builtin_amdgcn_update_dpp(NI, __float_as_int(v0), 0x114, 0xf, 0xf, false)));
          v1 = fmaxf(v1, __int_as_float(__builtin_amdgcn_update_dpp(NI, __float_as_int(v1), 0x114, 0xf, 0xf, false)));
          v2 = fmaxf(v2, __int_as_float(__builtin_amdgcn_update_dpp(NI, __float_as_int(v2), 0x114, 0xf, 0xf, false)));
          v3 = fmaxf(v3, __int_as_float(__builtin_amdgcn_update_dpp(NI, __float_as_int(v3), 0x114, 0xf, 0xf, false)));
          v0 = fmaxf(v0, __int_as_float(__builtin_amdgcn_update_dpp(NI, __float_as_int(v0), 0x118, 0xf, 0xf, false)));
          v1 = fmaxf(v1, __int_as_float(__builtin_amdgcn_update_dpp(NI, __float_as_int(v1), 0x118, 0xf, 0xf, false)));
          v2 = fmaxf(v2, __int_as_float(__builtin_amdgcn_update_dpp(NI, __float_as_int(v2), 0x118, 0xf, 0xf, false)));
          v3 = fmaxf(v3, __int_as_float(__builtin_amdgcn_update_dpp(NI, __float_as_int(v3), 0x118, 0xf, 0xf, false)));
          if ((lane & 15) == 15) {
            const float4 b24 = *(const float4*)&b2[ng * 16 + g4 * 4];
            float4 o;
            o.x = fmaxf(v0 + b24.x, 0.f);
            o.y = fmaxf(v1 + b24.y, 0.f);
            o.z = fmaxf(v2 + b24.z, 0.f);
            o.w = fmaxf(v3 + b24.w, 0.f);
            *(float4*)&out[gout * H2D + ng * 16 + g4 * 4] = o;
          }
        }
      }
      __syncthreads();  // protect A/Hs/qbuf/s_nbr/s_nc reuse next group
    }
  }
}

extern "C" void kernel_launch(void* const* d_in, const int* in_sizes, int n_in,
                              void* d_out, int out_size, void* d_ws, size_t ws_size,
                              hipStream_t stream) {
  const float* x = (const float*)d_in[0];
  const float* pos = (const float*)d_in[1];
  const float* W1 = (const float*)d_in[2];
  const float* b1 = (const float*)d_in[3];
  const float* W2 = (const float*)d_in[4];
  const float* b2 = (const float*)d_in[5];
  float* out = (float*)d_out;
  char* ws = (char*)d_ws;
  u16* W1T = (u16*)(ws + 0);        // 24576 B
  u16* W2T = (u16*)(ws + 24576);    // 65536 B
  int* samp = (int*)(ws + 90112);   // 65536 B
  u32* prog = (u32*)(ws + 155648);  // 64 B, re-zeroed every call below

  hipMemsetAsync(ws + 155648, 0, 64, stream);
  setup_kernel<<<dim3(176), dim3(256), 0, stream>>>(W1, W2, W1T, W2T);
  fused_kernel<<<dim3(256), dim3(512), 0, stream>>>(x, pos, b1, b2, W1T, W2T, samp,
                                                    prog, out);
}